// Round 13
// baseline (438.232 us; speedup 1.0000x reference)
//
#include <hip/hip_runtime.h>

#define M_DIM 16384   // 8 * 2048
#define N_DIM 4096
#define K_DIM 4096
#define BK 64
#define NKT (K_DIM / BK)   // 64 K-tiles

typedef unsigned char u8;
typedef __attribute__((ext_vector_type(4))) int   i32x4;

#define AS1 __attribute__((address_space(1)))
#define AS3 __attribute__((address_space(3)))

// ---- prepass: per-row symmetric quant of A to i8 (row-major, coalesced) ----
__global__ __launch_bounds__(256)
void quant_a_kernel(const float* __restrict__ in, char* __restrict__ out,
                    float* __restrict__ srow, int* __restrict__ rsum) {
    const int row  = blockIdx.x;
    const int t    = threadIdx.x;
    const int lane = t & 63, wv = t >> 6;
    const float4* rp = (const float4*)(in + (size_t)row * K_DIM);

    float4 v[4];
#pragma unroll
    for (int j = 0; j < 4; ++j) v[j] = rp[t + 256 * j];

    float amax = 0.f;
#pragma unroll
    for (int j = 0; j < 4; ++j) {
        amax = fmaxf(amax, fmaxf(fmaxf(fabsf(v[j].x), fabsf(v[j].y)),
                                 fmaxf(fabsf(v[j].z), fabsf(v[j].w))));
    }
#pragma unroll
    for (int off = 32; off; off >>= 1) amax = fmaxf(amax, __shfl_xor(amax, off));
    __shared__ float wred[4];
    __shared__ int   sred[4];
    if (lane == 0) wred[wv] = amax;
    __syncthreads();
    amax = fmaxf(fmaxf(wred[0], wred[1]), fmaxf(wred[2], wred[3]));
    const float inv = amax > 0.f ? 127.f / amax : 0.f;

    int lsum = 0;
    unsigned* orow = (unsigned*)(out + (size_t)row * K_DIM);
#pragma unroll
    for (int j = 0; j < 4; ++j) {
        int q0 = __float2int_rn(v[j].x * inv);
        int q1 = __float2int_rn(v[j].y * inv);
        int q2 = __float2int_rn(v[j].z * inv);
        int q3 = __float2int_rn(v[j].w * inv);
        lsum += q0 + q1 + q2 + q3;
        unsigned pk = (unsigned)(q0 & 0xFF) | ((unsigned)(q1 & 0xFF) << 8) |
                      ((unsigned)(q2 & 0xFF) << 16) | ((unsigned)(q3 & 0xFF) << 24);
        orow[t + 256 * j] = pk;
    }
#pragma unroll
    for (int off = 32; off; off >>= 1) lsum += __shfl_xor(lsum, off);
    if (lane == 0) sred[wv] = lsum;
    __syncthreads();
    if (t == 0) {
        rsum[row] = sred[0] + sred[1] + sred[2] + sred[3];
        srow[row] = amax > 0.f ? amax / 127.f : 1.f;
    }
}

// ---- prepass: W int32 -> raw i8 pack (row-major) ----
__global__ __launch_bounds__(256)
void pack_w_kernel(const int* __restrict__ q, char* __restrict__ out, int n4) {
    int stride = gridDim.x * blockDim.x;
    for (int i = blockIdx.x * blockDim.x + threadIdx.x; i < n4; i += stride) {
        int4 a = ((const int4*)q)[i];
        unsigned pk = (unsigned)(a.x & 0xFF) | ((unsigned)(a.y & 0xFF) << 8) |
                      ((unsigned)(a.z & 0xFF) << 16) | ((unsigned)(a.w & 0xFF) << 24);
        ((unsigned*)out)[i] = pk;
    }
}

// ---- 128x128 i8 GEMM, ring-3 LDS, 3 blocks/CU (12 waves/CU = 3/SIMD) ----
// Occupancy is the lever: R5-R12 all had 2 waves/SIMD and all plateaued at
// 288-305us / 41-44% MfmaUtil regardless of memory system. 3 desynced
// blocks/CU cover each other's read bursts and barrier drains (m114).
// 256 thr = 4 waves (2x2), per-wave out 64x64: acc i32x4[4][4] = 64 AGPR,
// ~125 regs total -> 3 waves/SIMD fits. LDS = 3 slots x (A128x64+B128x64)
// = 48 KiB -> 3 blocks/CU. Verified swizzle involution (R4/R5).
// Ledger (4 stage-loads/wave/tile, stage(u+2) during tile u): end-of-tile
// vmcnt(4) drains stage(u+1) one tile ahead of its readers; stage(u+2)
// writes slot of tile u-1 whose reads retired before the prior barrier;
// tail: vmcnt(0) at u==NKT-2.
__global__ __launch_bounds__(256, 3)
void gemm_i8_kernel(const char* __restrict__ A, const char* __restrict__ B,
                    const float* __restrict__ srow, const int* __restrict__ rsum,
                    const float* __restrict__ wsc_p, const int* __restrict__ wzp_p,
                    const int* __restrict__ qb, const float* __restrict__ bsc_p,
                    const int* __restrict__ bzp_p, float* __restrict__ C) {
    __shared__ __align__(16) u8 lds[3 * 16384];   // 48 KiB

    // XCD-bijective swizzle + 8(bm)x4(bn) supertiles (nwg=4096, %8==0)
    const int nwg = gridDim.x;
    const int cpx = nwg >> 3;                 // 512
    const int bid = blockIdx.x;
    const int swz = (bid & 7) * cpx + (bid >> 3);
    const int st = swz >> 5, wi = swz & 31;   // 128 supertiles of 8x4 blocks
    const int bm = (st >> 3) * 8 + (wi >> 2); // 0..127
    const int bn = (st & 7) * 4 + (wi & 3);   // 0..31
    const int m0 = bm * 128, n0 = bn * 128;

    const int tid  = threadIdx.x;
    const int wv   = tid >> 6;
    const int lane = tid & 63;
    const int wr   = wv >> 1;     // 0..1 : wave row (64 M-rows)
    const int wc   = wv & 1;      // 0..1 : wave col (64 N-cols)
    const int l15  = lane & 15;

    // read-side swizzled k-slot byte offset
    const int koff = (((lane >> 4) ^ ((lane >> 1) & 3)) << 4);

    // staging: wave wv stages 4x1KB. wv<2 -> A half (wv&1), else B half.
    // lane l -> row i*16 + (l>>2) within the half; source col pre-swizzled.
    const int srw  = (wv & 1) * 64 + (lane >> 2);            // row in operand
    const int gcol = (((lane & 3) ^ ((lane >> 3) & 3)) << 4);
    const char* Gsrc = (wv < 2 ? A + (size_t)(m0 + srw) * K_DIM
                               : B + (size_t)(n0 + srw) * K_DIM) + gcol;
    const int dbase = (wv >> 1) * 8192 + (wv & 1) * 4096;    // within slot

    i32x4 acc[4][4] = {};

    auto STAGE = [&](int ns, int k3) {
#pragma unroll
        for (int i = 0; i < 4; ++i)
            __builtin_amdgcn_global_load_lds(
                (const AS1 void*)(Gsrc + (size_t)i * 16 * K_DIM + k3),
                (AS3 void*)(lds + ns * 16384 + dbase + i * 1024), 16, 0, 0);
    };

    // ---- prologue: stage tiles 0,1 into slots 0,1 (8 loads/wave) ----
    STAGE(0, 0);
    STAGE(1, BK);
    asm volatile("s_waitcnt vmcnt(4)" ::: "memory");   // tile 0 landed
    __builtin_amdgcn_s_barrier();
    __builtin_amdgcn_sched_barrier(0);

    for (int u = 0; u < NKT; ++u) {
        const u8* Asl = lds + (u % 3) * 16384;
        const u8* Bsl = Asl + 8192;

        // fragment reads: 4 B then 4 A (8 x ds_read_b128)
        i32x4 af[4], bfr[4];
#pragma unroll
        for (int ni = 0; ni < 4; ++ni)
            bfr[ni] = *(const i32x4*)(Bsl + (wc * 64 + ni * 16 + l15) * 64 + koff);
#pragma unroll
        for (int mi = 0; mi < 4; ++mi)
            af[mi] = *(const i32x4*)(Asl + (wr * 64 + mi * 16 + l15) * 64 + koff);

        // stage tile u+2 into the slot tile u-1 vacated
        if (u + 2 < NKT) STAGE((u + 2) % 3, (u + 2) * BK);

        // MFMAs: compiler inserts fine-grained lgkm waits per dependency
        __builtin_amdgcn_s_setprio(1);
#pragma unroll
        for (int mi = 0; mi < 4; ++mi)
#pragma unroll
            for (int ni = 0; ni < 4; ++ni)
                acc[mi][ni] = __builtin_amdgcn_mfma_i32_16x16x64_i8(
                    af[mi], bfr[ni], acc[mi][ni], 0, 0, 0);
        __builtin_amdgcn_s_setprio(0);

        // tile end: reads retired (slot-reuse hazard), counted vmcnt, barrier
        asm volatile("s_waitcnt lgkmcnt(0)" ::: "memory");
        if (u < NKT - 2)       asm volatile("s_waitcnt vmcnt(4)" ::: "memory");
        else if (u == NKT - 2) asm volatile("s_waitcnt vmcnt(0)" ::: "memory");
        __builtin_amdgcn_s_barrier();
        __builtin_amdgcn_sched_barrier(0);
    }

    // ---- epilogue: dequant + zp correction + bias ----
    const float ws  = wsc_p[0];
    const float zpf = (float)wzp_p[0];
    const float bsc = bsc_p[0];
    const float bzp = (float)bzp_p[0];
    float bias_[4];
#pragma unroll
    for (int ni = 0; ni < 4; ++ni) {
        int col = n0 + wc * 64 + ni * 16 + l15;
        bias_[ni] = ((float)qb[col] - bzp) * bsc;
    }
#pragma unroll
    for (int mi = 0; mi < 4; ++mi) {
        int rbase = m0 + wr * 64 + mi * 16 + (lane >> 4) * 4;
        float fs_[4], fc_[4];
#pragma unroll
        for (int i = 0; i < 4; ++i) {
            float sf = ws * srow[rbase + i];
            fs_[i] = sf;
            fc_[i] = -sf * zpf * (float)rsum[rbase + i];
        }
#pragma unroll
        for (int ni = 0; ni < 4; ++ni) {
            int col = n0 + wc * 64 + ni * 16 + l15;
#pragma unroll
            for (int i = 0; i < 4; ++i)
                C[(size_t)(rbase + i) * N_DIM + col] =
                    fs_[i] * (float)acc[mi][ni][i] + fc_[i] + bias_[ni];
        }
    }
}

// ---- fallback (only if ws too small): correct, slow ----
__global__ void gemm_fallback_kernel(const float* __restrict__ A, const int* __restrict__ Wq,
                                     const float* __restrict__ wsc_p, const int* __restrict__ wzp_p,
                                     const int* __restrict__ qb, const float* __restrict__ bsc_p,
                                     const int* __restrict__ bzp_p, float* __restrict__ C) {
    int m = blockIdx.y;
    int n = blockIdx.x * 256 + threadIdx.x;
    float zp = (float)wzp_p[0];
    float sc = wsc_p[0];
    __shared__ float Arow[512];
    float acc = 0.f;
    for (int k0 = 0; k0 < K_DIM; k0 += 512) {
        __syncthreads();
        for (int t = threadIdx.x; t < 512; t += 256)
            Arow[t] = A[(size_t)m * K_DIM + k0 + t];
        __syncthreads();
        const int4* wp = (const int4*)(Wq + (size_t)n * K_DIM + k0);
        for (int kk = 0; kk < 512; kk += 4) {
            int4 q = wp[kk >> 2];
            acc += Arow[kk]     * ((float)q.x - zp);
            acc += Arow[kk + 1] * ((float)q.y - zp);
            acc += Arow[kk + 2] * ((float)q.z - zp);
            acc += Arow[kk + 3] * ((float)q.w - zp);
        }
    }
    acc *= sc;
    acc += ((float)qb[n] - (float)bzp_p[0]) * bsc_p[0];
    C[(size_t)m * N_DIM + n] = acc;
}

extern "C" void kernel_launch(void* const* d_in, const int* in_sizes, int n_in,
                              void* d_out, int out_size, void* d_ws, size_t ws_size,
                              hipStream_t stream) {
    (void)in_sizes; (void)n_in; (void)out_size;
    const float* input = (const float*)d_in[0];
    const int*   qw    = (const int*)d_in[1];
    const float* wsc   = (const float*)d_in[2];
    const int*   wzp   = (const int*)d_in[3];
    const int*   qb    = (const int*)d_in[4];
    const float* bsc   = (const float*)d_in[5];
    const int*   bzp   = (const int*)d_in[6];
    float* out = (float*)d_out;

    size_t offA = 0;
    size_t offW = (size_t)M_DIM * K_DIM;                 // 64 MB (i8)
    size_t offS = offW + (size_t)N_DIM * K_DIM;          // +16 MB
    size_t offR = offS + (size_t)M_DIM * sizeof(float);  // +64 KB
    size_t need = offR + (size_t)M_DIM * sizeof(int);    // ~80.1 MB

    if (ws_size >= need) {
        char*  Aq = (char*)d_ws + offA;
        char*  Wq8 = (char*)d_ws + offW;
        float* S  = (float*)((char*)d_ws + offS);
        int*   R  = (int*)((char*)d_ws + offR);
        quant_a_kernel<<<M_DIM, 256, 0, stream>>>(input, Aq, S, R);
        pack_w_kernel<<<2048, 256, 0, stream>>>(qw, Wq8, N_DIM * K_DIM / 4);
        gemm_i8_kernel<<<(M_DIM / 128) * (N_DIM / 128), 256, 0, stream>>>(
            Aq, Wq8, S, R, wsc, wzp, qb, bsc, bzp, out);
    } else {
        dim3 grid(N_DIM / 256, M_DIM);
        gemm_fallback_kernel<<<grid, 256, 0, stream>>>(input, qw, wsc, wzp, qb, bsc, bzp, out);
    }
}

// Round 14
// 378.760 us; speedup vs baseline: 1.1570x; 1.1570x over previous
//
#include <hip/hip_runtime.h>

#define M_DIM 16384   // 8 * 2048
#define N_DIM 4096
#define K_DIM 4096
#define BK 64
#define NKT (K_DIM / BK)   // 64 K-tiles

typedef unsigned char u8;
typedef __attribute__((ext_vector_type(4))) int   i32x4;

#define AS1 __attribute__((address_space(1)))
#define AS3 __attribute__((address_space(3)))

// ---- prepass: per-row symmetric quant of A to i8, plus row scale & rowsum ----
__global__ __launch_bounds__(256)
void quant_a_kernel(const float* __restrict__ in, char* __restrict__ out,
                    float* __restrict__ srow, int* __restrict__ rsum) {
    const int row  = blockIdx.x;
    const int t    = threadIdx.x;
    const int lane = t & 63, wv = t >> 6;
    const float4* rp = (const float4*)(in + (size_t)row * K_DIM);

    float4 v[4];
#pragma unroll
    for (int j = 0; j < 4; ++j) v[j] = rp[t + 256 * j];

    float amax = 0.f;
#pragma unroll
    for (int j = 0; j < 4; ++j) {
        amax = fmaxf(amax, fmaxf(fmaxf(fabsf(v[j].x), fabsf(v[j].y)),
                                 fmaxf(fabsf(v[j].z), fabsf(v[j].w))));
    }
#pragma unroll
    for (int off = 32; off; off >>= 1) amax = fmaxf(amax, __shfl_xor(amax, off));
    __shared__ float wred[4];
    __shared__ int   sred[4];
    if (lane == 0) wred[wv] = amax;
    __syncthreads();
    amax = fmaxf(fmaxf(wred[0], wred[1]), fmaxf(wred[2], wred[3]));
    const float inv = amax > 0.f ? 127.f / amax : 0.f;

    int lsum = 0;
    unsigned* orow = (unsigned*)(out + (size_t)row * K_DIM);
#pragma unroll
    for (int j = 0; j < 4; ++j) {
        int q0 = __float2int_rn(v[j].x * inv);
        int q1 = __float2int_rn(v[j].y * inv);
        int q2 = __float2int_rn(v[j].z * inv);
        int q3 = __float2int_rn(v[j].w * inv);
        lsum += q0 + q1 + q2 + q3;
        unsigned pk = (unsigned)(q0 & 0xFF) | ((unsigned)(q1 & 0xFF) << 8) |
                      ((unsigned)(q2 & 0xFF) << 16) | ((unsigned)(q3 & 0xFF) << 24);
        orow[t + 256 * j] = pk;
    }
#pragma unroll
    for (int off = 32; off; off >>= 1) lsum += __shfl_xor(lsum, off);
    if (lane == 0) sred[wv] = lsum;
    __syncthreads();
    if (t == 0) {
        rsum[row] = sred[0] + sred[1] + sred[2] + sred[3];
        srow[row] = amax > 0.f ? amax / 127.f : 1.f;
    }
}

// ---- prepass: W int32 -> raw i8 pack (no dequant; zp corrected in epilogue) ----
__global__ __launch_bounds__(256)
void pack_w_kernel(const int* __restrict__ q, char* __restrict__ out, int n4) {
    int stride = gridDim.x * blockDim.x;
    for (int i = blockIdx.x * blockDim.x + threadIdx.x; i < n4; i += stride) {
        int4 a = ((const int4*)q)[i];
        unsigned pk = (unsigned)(a.x & 0xFF) | ((unsigned)(a.y & 0xFF) << 8) |
                      ((unsigned)(a.z & 0xFF) << 16) | ((unsigned)(a.w & 0xFF) << 24);
        ((unsigned*)out)[i] = pk;
    }
}

// ---- 256x256 i8 GEMM, ring-4 LDS (BK=64), SUB-PHASE ISSUE INTERLEAVE ----
// R5 geometry (best: 288us). New: the issue ORDER inside each K-tile is
// pinned with sched_barrier(0) fences to {2 reads} | {4 MFMA} | {2 reads} |
// {4 MFMA} | ... so the LDS pipe is fed DURING the MFMA region instead of
// the burst-reads-then-burst-MFMAs order the compiler chooses unforced
// (R9 evidence). Per-group waits are the compiler's own data-dep counted
// lgkmcnt (m97 mechanism) — in-order LDS returns make them minimal.
// Ledger unchanged from R5: stage(u+3) issued in block B1 targets slot
// (u-1)&3 whose reads all retired before tile u began (last MFMA group of
// tile u-1 waited lgkmcnt(0) via data dep); vmcnt(8)->4->0 tail; ONE
// barrier per tile.
__global__ __launch_bounds__(512, 2)
void gemm_i8_kernel(const char* __restrict__ A, const char* __restrict__ B,
                    const float* __restrict__ srow, const int* __restrict__ rsum,
                    const float* __restrict__ wsc_p, const int* __restrict__ wzp_p,
                    const int* __restrict__ qb, const float* __restrict__ bsc_p,
                    const int* __restrict__ bzp_p, float* __restrict__ C) {
    __shared__ __align__(16) u8 lds[4 * 32768];   // 128 KiB

    // XCD-bijective swizzle + 8x4 supertiles for L2 reuse (nwg=1024, %8==0)
    const int nwg = gridDim.x;
    const int cpx = nwg >> 3;
    const int bid = blockIdx.x;
    const int swz = (bid & 7) * cpx + (bid >> 3);
    const int st = swz >> 5, wi = swz & 31;
    const int bm = (st >> 2) * 8 + (wi >> 2);
    const int bn = (st & 3) * 4 + (wi & 3);
    const int m0 = bm * 256, n0 = bn * 256;

    const int tid  = threadIdx.x;
    const int wv   = tid >> 6;
    const int lane = tid & 63;
    const int wr   = wv >> 2;     // 0..1 : wave row (128 M-rows)
    const int wcn  = wv & 3;      // 0..3 : wave col (64 N-cols)
    const int l15  = lane & 15;

    // per-lane swizzled k-slot byte offset for fragment reads
    const int koff = (((lane >> 4) ^ ((lane >> 1) & 3)) << 4);

    // staging: lane writes LDS linearly; source col pre-swizzled (bytes)
    const int srt  = tid >> 2;                               // 0..127
    const int gcol = (((tid & 3) ^ ((tid >> 3) & 3)) << 4);  // pre-swizzled col
    const char* AgT = A + (size_t)(m0 + srt) * K_DIM + gcol;
    const char* BgT = B + (size_t)(n0 + srt) * K_DIM + gcol;
    const int wvo = wv << 10;    // wave chunk: 64 lanes * 16 B

    i32x4 acc[8][4] = {};

    auto STAGE_A = [&](int ns, int k3) {
#pragma unroll
        for (int i = 0; i < 2; ++i)
            __builtin_amdgcn_global_load_lds(
                (const AS1 void*)(AgT + (size_t)i * 128 * K_DIM + k3),
                (AS3 void*)(lds + ns * 32768 + i * 8192 + wvo), 16, 0, 0);
    };
    auto STAGE_B = [&](int ns, int k3) {
#pragma unroll
        for (int i = 0; i < 2; ++i)
            __builtin_amdgcn_global_load_lds(
                (const AS1 void*)(BgT + (size_t)i * 128 * K_DIM + k3),
                (AS3 void*)(lds + ns * 32768 + 16384 + i * 8192 + wvo), 16, 0, 0);
    };

#define SB() __builtin_amdgcn_sched_barrier(0)
#define RD_AF(MI) af[MI] = *(const i32x4*)(Asl + (wr * 128 + (MI) * 16 + l15) * 64 + koff)
#define MFMA_G(MI)                                                             \
    _Pragma("unroll")                                                          \
    for (int ni = 0; ni < 4; ++ni)                                             \
        acc[MI][ni] = __builtin_amdgcn_mfma_i32_16x16x64_i8(                   \
            af[MI], bfr[ni], acc[MI][ni], 0, 0, 0)

    // ---- prologue: stage K-tiles 0,1,2 into slots 0,1,2 (12 loads) ----
    STAGE_A(0, 0);      STAGE_B(0, 0);
    STAGE_A(1, BK);     STAGE_B(1, BK);
    STAGE_A(2, 2 * BK); STAGE_B(2, 2 * BK);
    asm volatile("s_waitcnt vmcnt(8)" ::: "memory");   // tile 0 landed
    __builtin_amdgcn_s_barrier();
    SB();

#pragma unroll 4
    for (int u = 0; u < NKT; ++u) {
        const u8* Asl = lds + (u & 3) * 32768;
        const u8* Bsl = Asl + 16384;
        const bool pf = (u + 3) < NKT;
        const int ns = (u + 3) & 3;
        const int k3 = (u + 3) * BK;

        i32x4 af[8], bfr[4];

        // B1: first reads (bfr0-3, af0, af1) + staging issue
#pragma unroll
        for (int ni = 0; ni < 4; ++ni)
            bfr[ni] = *(const i32x4*)(Bsl + (wcn * 64 + ni * 16 + l15) * 64 + koff);
        RD_AF(0); RD_AF(1);
        if (pf) { STAGE_A(ns, k3); STAGE_B(ns, k3); }
        SB();
        // B2: MFMA group 0 (compiler waits lgkm for bfr0-3+af0 only)
        __builtin_amdgcn_s_setprio(1);
        MFMA_G(0);
        __builtin_amdgcn_s_setprio(0);
        SB();
        RD_AF(2); RD_AF(3);          // feed LDS pipe during MFMA region
        SB();
        __builtin_amdgcn_s_setprio(1);
        MFMA_G(1);
        __builtin_amdgcn_s_setprio(0);
        SB();
        RD_AF(4); RD_AF(5);
        SB();
        __builtin_amdgcn_s_setprio(1);
        MFMA_G(2);
        MFMA_G(3);
        __builtin_amdgcn_s_setprio(0);
        SB();
        RD_AF(6); RD_AF(7);
        SB();
        __builtin_amdgcn_s_setprio(1);
        MFMA_G(4);
        MFMA_G(5);
        MFMA_G(6);
        MFMA_G(7);                   // data-dep wait on af7 == full lgkm drain
        __builtin_amdgcn_s_setprio(0);
        SB();

        // tile end: counted vmcnt (stage(u+1) landed), ONE barrier
        if (u < NKT - 3)       asm volatile("s_waitcnt vmcnt(8)" ::: "memory");
        else if (u == NKT - 3) asm volatile("s_waitcnt vmcnt(4)" ::: "memory");
        else if (u == NKT - 2) asm volatile("s_waitcnt vmcnt(0)" ::: "memory");
        __builtin_amdgcn_s_barrier();
        SB();
    }
#undef SB
#undef RD_AF
#undef MFMA_G

    // ---- epilogue: dequant + zp correction + bias ----
    const float ws  = wsc_p[0];
    const float zpf = (float)wzp_p[0];
    const float bsc = bsc_p[0];
    const float bzp = (float)bzp_p[0];
    float bias_[4];
#pragma unroll
    for (int ni = 0; ni < 4; ++ni) {
        int col = n0 + wcn * 64 + ni * 16 + l15;
        bias_[ni] = ((float)qb[col] - bzp) * bsc;
    }
#pragma unroll
    for (int mi = 0; mi < 8; ++mi) {
        int rbase = m0 + wr * 128 + mi * 16 + (lane >> 4) * 4;
        float fs_[4], fc_[4];
#pragma unroll
        for (int i = 0; i < 4; ++i) {
            float sf = ws * srow[rbase + i];
            fs_[i] = sf;
            fc_[i] = -sf * zpf * (float)rsum[rbase + i];
        }
#pragma unroll
        for (int ni = 0; ni < 4; ++ni) {
            int col = n0 + wcn * 64 + ni * 16 + l15;
#pragma unroll
            for (int i = 0; i < 4; ++i)
                C[(size_t)(rbase + i) * N_DIM + col] =
                    fs_[i] * (float)acc[mi][ni][i] + fc_[i] + bias_[ni];
        }
    }
}

// ---- fallback (only if ws too small): correct, slow ----
__global__ void gemm_fallback_kernel(const float* __restrict__ A, const int* __restrict__ Wq,
                                     const float* __restrict__ wsc_p, const int* __restrict__ wzp_p,
                                     const int* __restrict__ qb, const float* __restrict__ bsc_p,
                                     const int* __restrict__ bzp_p, float* __restrict__ C) {
    int m = blockIdx.y;
    int n = blockIdx.x * 256 + threadIdx.x;
    float zp = (float)wzp_p[0];
    float sc = wsc_p[0];
    __shared__ float Arow[512];
    float acc = 0.f;
    for (int k0 = 0; k0 < K_DIM; k0 += 512) {
        __syncthreads();
        for (int t = threadIdx.x; t < 512; t += 256)
            Arow[t] = A[(size_t)m * K_DIM + k0 + t];
        __syncthreads();
        const int4* wp = (const int4*)(Wq + (size_t)n * K_DIM + k0);
        for (int kk = 0; kk < 512; kk += 4) {
            int4 q = wp[kk >> 2];
            acc += Arow[kk]     * ((float)q.x - zp);
            acc += Arow[kk + 1] * ((float)q.y - zp);
            acc += Arow[kk + 2] * ((float)q.z - zp);
            acc += Arow[kk + 3] * ((float)q.w - zp);
        }
    }
    acc *= sc;
    acc += ((float)qb[n] - (float)bzp_p[0]) * bsc_p[0];
    C[(size_t)m * N_DIM + n] = acc;
}

extern "C" void kernel_launch(void* const* d_in, const int* in_sizes, int n_in,
                              void* d_out, int out_size, void* d_ws, size_t ws_size,
                              hipStream_t stream) {
    (void)in_sizes; (void)n_in; (void)out_size;
    const float* input = (const float*)d_in[0];
    const int*   qw    = (const int*)d_in[1];
    const float* wsc   = (const float*)d_in[2];
    const int*   wzp   = (const int*)d_in[3];
    const int*   qb    = (const int*)d_in[4];
    const float* bsc   = (const float*)d_in[5];
    const int*   bzp   = (const int*)d_in[6];
    float* out = (float*)d_out;

    size_t offA = 0;
    size_t offW = (size_t)M_DIM * K_DIM;                 // 64 MB (i8)
    size_t offS = offW + (size_t)N_DIM * K_DIM;          // +16 MB
    size_t offR = offS + (size_t)M_DIM * sizeof(float);  // +64 KB
    size_t need = offR + (size_t)M_DIM * sizeof(int);    // ~80.1 MB

    if (ws_size >= need) {
        char*  Aq = (char*)d_ws + offA;
        char*  Wq8 = (char*)d_ws + offW;
        float* S  = (float*)((char*)d_ws + offS);
        int*   R  = (int*)((char*)d_ws + offR);
        quant_a_kernel<<<M_DIM, 256, 0, stream>>>(input, Aq, S, R);
        pack_w_kernel<<<2048, 256, 0, stream>>>(qw, Wq8, N_DIM * K_DIM / 4);
        gemm_i8_kernel<<<(M_DIM / 256) * (N_DIM / 256), 512, 0, stream>>>(
            Aq, Wq8, S, R, wsc, wzp, qb, bsc, bzp, out);
    } else {
        dim3 grid(N_DIM / 256, M_DIM);
        gemm_fallback_kernel<<<grid, 256, 0, stream>>>(input, qw, wsc, wzp, qb, bsc, bzp, out);
    }
}